// Round 6
// baseline (94.168 us; speedup 1.0000x reference)
//
#include <hip/hip_runtime.h>

// out[b,c,l] = sum_r x[b,r,l] * weight[idx[b,l], r, c] + bias[idx[b,l], c]
//   x:       (4, 256, 32, 32) fp32   flat (b*256 + r)*1024 + l
//   indexes: (4096,) int             j in [0,8)
//   weight:  (8, 256, 256) fp32      (j*256 + r)*256 + c
//   bias:    (8, 256) fp32
//   out:     (4, 256, 32, 32) fp32   (b*256 + c)*1024 + l
//
// R6: pipeline compressed 5 -> 3 kernels. GEMM gathers A directly from x
// (no transpose kernel, no g_xt) and writes out directly in (b,c,l) layout
// (no opose, no g_outtmp). The inner loop is compute-dominated (512 FMA
// cycles per K-chunk per wave), so gathered A-loads and scattered epilogue
// stores hide under it; saves 2 launches + 16 MB of intermediate traffic.

#define N_TOK   4096
#define R_MAX   256
#define C_DIM   256
#define N_J     8
#define MT      64      // tokens per GEMM block
#define NT      64      // channels per GEMM block
#define KC      32      // K chunk
#define LDA     68      // As row stride (floats)
#define LDB     68
#define NTILE_Y 72      // >= max token tiles = 64 + 7

__device__ int g_perm[N_J * N_TOK];   // bucketed token ids
__device__ int g_cnt[N_J];

// ---------------- Kernel A0: zero the global counters ----------------
__global__ __launch_bounds__(64) void zero_kernel()
{
    if (threadIdx.x < N_J) g_cnt[threadIdx.x] = 0;
}

// ---------------- Kernel A1: parallel bucket scatter ----------------
// 16 blocks x 256 threads, one token per thread.
__global__ __launch_bounds__(256) void scatter_kernel(const int* __restrict__ idx)
{
    __shared__ int loc[N_J];     // block-local counts
    __shared__ int base[N_J];    // block's base within each global bucket

    const int t = threadIdx.x;
    if (t < N_J) loc[t] = 0;
    __syncthreads();

    const int tok  = blockIdx.x * 256 + t;
    const int j    = idx[tok];
    const int lane = t & 63;
    const unsigned long long below = (1ULL << lane) - 1ULL;

    int lpos = 0;
    #pragma unroll
    for (int jj = 0; jj < N_J; ++jj) {
        const unsigned long long m = __ballot(j == jj);
        if (j == jj) {
            const int leader = __ffsll(m) - 1;
            int b = 0;
            if (lane == leader) b = atomicAdd(&loc[jj], (int)__popcll(m));
            b = __shfl(b, leader);
            lpos = b + (int)__popcll(m & below);
        }
    }
    __syncthreads();
    if (t < N_J) base[t] = atomicAdd(&g_cnt[t], loc[t]);   // device-scope
    __syncthreads();

    g_perm[j * N_TOK + base[j] + lpos] = tok;
}

// ---------------- Kernel C: fused gather-GEMM-scatter ----------------
// grid (4 c-tiles, 72 token tiles), block 256.
// Out[64 tok x 64 c] = X[64 x 256 gathered] @ W_j[256 x 64] + bias_j,
// written directly to out (b,c,l).
__global__ __launch_bounds__(256) void gemm_kernel(const float* __restrict__ x,
                                                   const float* __restrict__ weight,
                                                   const float* __restrict__ bias,
                                                   float* __restrict__ out)
{
    const int v = blockIdx.y;
    int j = -1, start = 0, total = 0;
    #pragma unroll
    for (int jj = 0; jj < N_J; ++jj) {
        const int cnt = g_cnt[jj];
        const int ntl = (cnt + MT - 1) >> 6;
        if (j < 0 && v < total + ntl) { j = jj; start = (v - total) << 6; }
        total += ntl;
    }
    if (j < 0) return;

    const int cb   = blockIdx.x * NT;
    const int rows = min(MT, g_cnt[j] - start);

    __shared__ int   rowtok[MT];
    __shared__ float As[2][KC][LDA];
    __shared__ float Bs[2][KC][LDB];

    const int t = threadIdx.x;
    if (t < MT) rowtok[t] = g_perm[j * N_TOK + start + min(t, rows - 1)];
    __syncthreads();

    // A staging: thread t -> token row (t&63), k-group (t>>6): 8 k's/thread.
    const int a_row = t & 63;
    const int a_kg  = (t >> 6) * 8;      // k_local base: 0,8,16,24
    {
        const int tokA = rowtok[a_row];
        // x element offset for (b, k, l): b*262144 + k*1024 + l
        const float* __restrict__ xp =
            x + ((tokA >> 10) << 18) + (tokA & 1023) + (a_kg << 10);
        // B staging: thread t -> k rows (t>>4, +16), 4 channels at (t&15)*4.
        const int b_k = t >> 4;
        const int b_c = (t & 15) * 4;
        const float* __restrict__ wj = weight + j * (R_MAX * C_DIM) + cb;

        // ---- Prologue: stage chunk 0 into buffer 0 ----
        float ra[8];
        #pragma unroll
        for (int i = 0; i < 8; ++i) ra[i] = xp[i << 10];
        float4 rb0 = *(const float4*)(wj + b_k * C_DIM + b_c);
        float4 rb1 = *(const float4*)(wj + (b_k + 16) * C_DIM + b_c);

        #pragma unroll
        for (int i = 0; i < 8; ++i) As[0][a_kg + i][a_row] = ra[i];
        *(float4*)&Bs[0][b_k][b_c]      = rb0;
        *(float4*)&Bs[0][b_k + 16][b_c] = rb1;
        __syncthreads();

        const int tx = t & 15;           // 4 channels at tx*4
        const int ty = t >> 4;           // 4 tokens at ty*4

        float4 acc0 = {0.f, 0.f, 0.f, 0.f};
        float4 acc1 = {0.f, 0.f, 0.f, 0.f};
        float4 acc2 = {0.f, 0.f, 0.f, 0.f};
        float4 acc3 = {0.f, 0.f, 0.f, 0.f};

        int p = 0;
        for (int k0 = 0; k0 < R_MAX; k0 += KC) {
            const int kn = k0 + KC;
            if (kn < R_MAX) {            // register-prefetch next chunk
                #pragma unroll
                for (int i = 0; i < 8; ++i) ra[i] = xp[(kn + i) << 10];
                rb0 = *(const float4*)(wj + (kn + b_k) * C_DIM + b_c);
                rb1 = *(const float4*)(wj + (kn + b_k + 16) * C_DIM + b_c);
            }
            #pragma unroll
            for (int kk = 0; kk < KC; ++kk) {
                const float4 av = *(const float4*)&As[p][kk][ty * 4];
                const float4 bv = *(const float4*)&Bs[p][kk][tx * 4];
                acc0.x += av.x * bv.x; acc0.y += av.x * bv.y; acc0.z += av.x * bv.z; acc0.w += av.x * bv.w;
                acc1.x += av.y * bv.x; acc1.y += av.y * bv.y; acc1.z += av.y * bv.z; acc1.w += av.y * bv.w;
                acc2.x += av.z * bv.x; acc2.y += av.z * bv.y; acc2.z += av.z * bv.z; acc2.w += av.z * bv.w;
                acc3.x += av.w * bv.x; acc3.y += av.w * bv.y; acc3.z += av.w * bv.z; acc3.w += av.w * bv.w;
            }
            if (kn < R_MAX) {
                const int q = p ^ 1;
                #pragma unroll
                for (int i = 0; i < 8; ++i) As[q][a_kg + i][a_row] = ra[i];
                *(float4*)&Bs[q][b_k][b_c]      = rb0;
                *(float4*)&Bs[q][b_k + 16][b_c] = rb1;
                __syncthreads();
                p = q;
            }
        }

        // ---- Epilogue: + bias, scatter directly to out (b,c,l) ----
        const float4 bb = *(const float4*)(bias + j * C_DIM + cb + tx * 4);
        const int c0 = cb + tx * 4;
        const int r0 = ty * 4;
        float4 accs[4] = {acc0, acc1, acc2, acc3};
        #pragma unroll
        for (int i = 0; i < 4; ++i) {
            if (r0 + i < rows) {
                const int tokO = rowtok[r0 + i];
                float* __restrict__ op =
                    out + ((tokO >> 10) << 18) + (tokO & 1023) + (c0 << 10);
                op[0 << 10] = accs[i].x + bb.x;
                op[1 << 10] = accs[i].y + bb.y;
                op[2 << 10] = accs[i].z + bb.z;
                op[3 << 10] = accs[i].w + bb.w;
            }
        }
    }
}

extern "C" void kernel_launch(void* const* d_in, const int* in_sizes, int n_in,
                              void* d_out, int out_size, void* d_ws, size_t ws_size,
                              hipStream_t stream)
{
    const float* x      = (const float*)d_in[0];
    const int*   idx    = (const int*)  d_in[1];
    const float* weight = (const float*)d_in[2];
    const float* bias   = (const float*)d_in[3];
    float*       out    = (float*)      d_out;

    zero_kernel<<<1, 64, 0, stream>>>();
    scatter_kernel<<<N_TOK / 256, 256, 0, stream>>>(idx);
    gemm_kernel<<<dim3(4, NTILE_Y, 1), 256, 0, stream>>>(x, weight, bias, out);
}